// Round 6
// baseline (284.271 us; speedup 1.0000x reference)
//
#include <hip/hip_runtime.h>

#define H 1024
#define QD 16
#define BATCH 4
#define SEQ 2048
#define MROWS 8192  // BATCH*SEQ

typedef __bf16 bf16x8 __attribute__((ext_vector_type(8)));
typedef __bf16 bf16x4 __attribute__((ext_vector_type(4)));
typedef float f32x4 __attribute__((ext_vector_type(4)));

__device__ __forceinline__ void async_g2l_16(const void* g, void* l) {
  __builtin_amdgcn_global_load_lds(
      (const __attribute__((address_space(1))) unsigned int*)g,
      (__attribute__((address_space(3))) unsigned int*)l, 16, 0, 0);
}

// ---------------- fp32 -> bf16 hi/lo split (x) ----------------
__global__ __launch_bounds__(256) void cvt_split(const float* __restrict__ src,
                                                 __bf16* __restrict__ hi,
                                                 __bf16* __restrict__ lo, int n) {
  int i = (blockIdx.x * 256 + threadIdx.x) * 4;
  if (i < n) {
    float4 f = *(const float4*)(src + i);
    bf16x4 h, l;
    h[0] = (__bf16)f.x; l[0] = (__bf16)(f.x - (float)h[0]);
    h[1] = (__bf16)f.y; l[1] = (__bf16)(f.y - (float)h[1]);
    h[2] = (__bf16)f.z; l[2] = (__bf16)(f.z - (float)h[2]);
    h[3] = (__bf16)f.w; l[3] = (__bf16)(f.w - (float)h[3]);
    *(bf16x4*)(hi + i) = h;
    *(bf16x4*)(lo + i) = l;
  }
}

// ---------------- fp32 [R][C] -> bf16 transposed [C][R] ----------------
__global__ __launch_bounds__(256) void transpose_cvt_f32_bf16(
    const float* __restrict__ src, __bf16* __restrict__ dst, int R, int C) {
  __shared__ float t[32][33];
  const int rb = blockIdx.y * 32, cb = blockIdx.x * 32;
  const int c = threadIdx.x & 31;
  const int r0 = threadIdx.x >> 5;
#pragma unroll
  for (int rr = r0; rr < 32; rr += 8)
    t[rr][c] = src[(long)(rb + rr) * C + cb + c];
  __syncthreads();
#pragma unroll
  for (int rr = r0; rr < 32; rr += 8)
    dst[(long)(cb + rr) * R + rb + c] = (__bf16)t[c][rr];
}

// ---------------- CqkT (Bt layout [32][1024]) in bf16 hi/lo ----------------
__global__ __launch_bounds__(256) void k2_cqk(const float* __restrict__ Wq,
                                              const float* __restrict__ Wk,
                                              const float* __restrict__ We,
                                              __bf16* __restrict__ Cth,
                                              __bf16* __restrict__ Ctl) {
  const int gw = blockIdx.x * 4 + (threadIdx.x >> 6);  // 0..2047
  const int lane = threadIdx.x & 63;
  const int mat = gw & 1, k = gw >> 1;
  const float* Wrow = (mat ? Wk : Wq) + (long)k * H;
  const int col = lane & 15, q4 = lane >> 4;
  float acc = 0.f;
  for (int n0 = 0; n0 < 256; ++n0) {
    int n = q4 * 256 + n0;
    acc += Wrow[n] * We[n * QD + col];
  }
  acc += __shfl_xor(acc, 16);
  acc += __shfl_xor(acc, 32);
  if (lane < 16) {
    __bf16 hi = (__bf16)acc;
    __bf16 lo = (__bf16)(acc - (float)hi);
    long idx = (long)(mat * 16 + col) * H + k;
    Cth[idx] = hi;
    Ctl[idx] = lo;
  }
}

// ---------------- dvec[j] = (bq|bk)@We + be ----------------
__global__ void k2b_dvec(const float* __restrict__ bq, const float* __restrict__ bk,
                         const float* __restrict__ We, const float* __restrict__ be,
                         float* __restrict__ dvec) {
  int j = threadIdx.x;
  if (j < 32) {
    int mat = j >> 4, col = j & 15;
    const float* b = mat ? bk : bq;
    float acc = be[col];
    for (int n = 0; n < H; ++n) acc += b[n] * We[n * QD + col];
    dvec[j] = acc;
  }
}

// ---------------- embed via MFMA (hi/lo split), fused normalize ----------------
// Outputs bf16 qq/kk in [S][32] layout with zero-padded upper K half.
__global__ __launch_bounds__(256) void k3_embed_mfma(
    const __bf16* __restrict__ xh, const __bf16* __restrict__ xl,
    const __bf16* __restrict__ Cth, const __bf16* __restrict__ Ctl,
    const float* __restrict__ dvec, __bf16* __restrict__ qq32,
    __bf16* __restrict__ kk32) {
  __shared__ __bf16 Ah[32 * 64];
  __shared__ __bf16 Al[32 * 64];
  __shared__ __bf16 Bh[32 * 64];
  __shared__ __bf16 Bl[32 * 64];
  const int tid = threadIdx.x;
  const int lane = tid & 63;
  const int w = tid >> 6;
  const int rowhalf = w >> 1;  // 0/1 -> rows 0-15 / 16-31
  const int ntile = w & 1;     // 0 -> qq, 1 -> kk
  const int l15 = lane & 15, quad = lane >> 4;
  const long rowBase = (long)blockIdx.x * 32;

  const int srow = tid >> 3;                       // 0..31 (LDS row)
  const int segsw = ((tid & 7) ^ (srow & 7)) * 8;  // swizzled global k-seg
  const __bf16* agh = xh + (rowBase + srow) * H + segsw;
  const __bf16* agl = xl + (rowBase + srow) * H + segsw;
  const __bf16* bgh = Cth + (long)srow * H + segsw;
  const __bf16* bgl = Ctl + (long)srow * H + segsw;
  __bf16* lah = &Ah[srow * 64 + (tid & 7) * 8];
  __bf16* lal = &Al[srow * 64 + (tid & 7) * 8];
  __bf16* lbh = &Bh[srow * 64 + (tid & 7) * 8];
  __bf16* lbl = &Bl[srow * 64 + (tid & 7) * 8];

  f32x4 acc;
  acc[0] = 0.f; acc[1] = 0.f; acc[2] = 0.f; acc[3] = 0.f;
  const int arow = (rowhalf * 16 + l15) * 64;
  const int brow = (ntile * 16 + l15) * 64;
  const int h7 = l15 & 7;

  for (int k0 = 0; k0 < H; k0 += 64) {
    async_g2l_16(agh + k0, lah);
    async_g2l_16(agl + k0, lal);
    async_g2l_16(bgh + k0, lbh);
    async_g2l_16(bgl + k0, lbl);
    __syncthreads();
#pragma unroll
    for (int s = 0; s < 2; ++s) {
      const int slot = ((s * 4 + quad) ^ h7) * 8;
      bf16x8 fah = *(const bf16x8*)&Ah[arow + slot];
      bf16x8 fal = *(const bf16x8*)&Al[arow + slot];
      bf16x8 fbh = *(const bf16x8*)&Bh[brow + slot];
      bf16x8 fbl = *(const bf16x8*)&Bl[brow + slot];
      acc = __builtin_amdgcn_mfma_f32_16x16x32_bf16(fah, fbh, acc, 0, 0, 0);
      acc = __builtin_amdgcn_mfma_f32_16x16x32_bf16(fal, fbh, acc, 0, 0, 0);
      acc = __builtin_amdgcn_mfma_f32_16x16x32_bf16(fah, fbl, acc, 0, 0, 0);
    }
    __syncthreads();
  }

  const float dv = dvec[ntile * 16 + l15];
  __bf16* outp = ntile ? kk32 : qq32;
#pragma unroll
  for (int r = 0; r < 4; ++r) {
    float z = acc[r] + dv;
    float s2 = z * z;
    s2 += __shfl_xor(s2, 1);
    s2 += __shfl_xor(s2, 2);
    s2 += __shfl_xor(s2, 4);
    s2 += __shfl_xor(s2, 8);
    float val = z * rsqrtf(s2 + 1e-8f);
    long row = rowBase + rowhalf * 16 + quad * 4 + r;
    outp[row * 32 + l15] = (__bf16)val;
    outp[row * 32 + 16 + l15] = (__bf16)0.f;  // zero pad K 16->32
  }
}

// ---------------- fused attention, producer/consumer waves ----------------
// Tile 64q x 256h, 512 threads. Waves 0-3 (producers): S^T chunk c+1 -> exp ->
// Plds[(c+1)&1] (double-buffered). Waves 4-7 (consumers): PV MFMA on Plds[c&1],
// V read DIRECTLY from global (L2/L3-hot). One barrier per chunk; exp VALU and
// PV MFMA co-scheduled on the same SIMDs.
#define PSTR 136   // Plds row stride bf16 (68 dwords == 4 mod 32)
#define NCH (SEQ / 128)

__device__ __forceinline__ void produce_chunk(const __bf16* __restrict__ kkb,
                                              const bf16x8 bq[2],
                                              __bf16* __restrict__ Pbuf,
                                              float rsPart[2], int k0, int ws_k,
                                              int ws_q, int l15, int quad) {
#pragma unroll
  for (int i = 0; i < 4; ++i) {
    bf16x8 ak =
        *(const bf16x8*)(kkb + (long)(k0 + ws_k * 64 + i * 16 + l15) * 32 + quad * 8);
#pragma unroll
    for (int n = 0; n < 2; ++n) {
      f32x4 s = {0.f, 0.f, 0.f, 0.f};
      s = __builtin_amdgcn_mfma_f32_16x16x32_bf16(ak, bq[n], s, 0, 0, 0);
      bf16x4 pw;
      float part = 0.f;
#pragma unroll
      for (int r = 0; r < 4; ++r) {
        float wgt = __expf(s[r] * s[r]);
        part += wgt;
        pw[r] = (__bf16)wgt;
      }
      rsPart[n] += part;
      *(bf16x4*)&Pbuf[(ws_q * 32 + n * 16 + l15) * PSTR + ws_k * 64 + i * 16 +
                      quad * 4] = pw;
    }
  }
}

__global__ __launch_bounds__(512, 4) void fused_attn(
    const __bf16* __restrict__ qq32, const __bf16* __restrict__ kk32,
    const __bf16* __restrict__ v_t, __bf16* __restrict__ attn) {
  __shared__ __bf16 Plds[2][64 * PSTR];
  __shared__ float rsum2[64 * 2];
  const int tid = threadIdx.x;
  const int lane = tid & 63;
  const int w = tid >> 6;  // 0..7
  const int l15 = lane & 15, quad = lane >> 4;
  const int b = blockIdx.z;
  const long qbase = (long)blockIdx.y * 64;
  const long hbase = (long)blockIdx.x * 256;

  const __bf16* kkb = kk32 + (long)b * SEQ * 32;
  const __bf16* vtb = v_t + (long)b * H * SEQ + hbase * SEQ;

  if (w < 4) {
    // ---------------- producer ----------------
    const int ws_k = w & 1, ws_q = w >> 1;
    bf16x8 bq[2];
    {
      const __bf16* qqp =
          qq32 + ((long)b * SEQ + qbase + ws_q * 32 + l15) * 32 + quad * 8;
#pragma unroll
      for (int n = 0; n < 2; ++n)
        bq[n] = *(const bf16x8*)(qqp + (long)n * 16 * 32);
    }
    float rsPart[2] = {0.f, 0.f};
    // prologue: chunk 0 into buf 0
    produce_chunk(kkb, bq, Plds[0], rsPart, 0, ws_k, ws_q, l15, quad);
    __syncthreads();
    for (int c = 0; c < NCH; ++c) {
      if (c + 1 < NCH)
        produce_chunk(kkb, bq, Plds[(c + 1) & 1], rsPart, (c + 1) * 128, ws_k,
                      ws_q, l15, quad);
      __syncthreads();
    }
    // rowsum: reduce over quads (k-direction), publish per (q, k-half)
#pragma unroll
    for (int n = 0; n < 2; ++n) {
      float vs = rsPart[n];
      vs += __shfl_xor(vs, 16);
      vs += __shfl_xor(vs, 32);
      if (lane < 16) rsum2[(ws_q * 32 + n * 16 + l15) * 2 + ws_k] = vs;
    }
    __syncthreads();
  } else {
    // ---------------- consumer ----------------
    const int wc = w - 4;  // h quarter
    f32x4 acc[4][4];
#pragma unroll
    for (int i = 0; i < 4; ++i)
#pragma unroll
      for (int j = 0; j < 4; ++j) {
        acc[i][j][0] = 0.f; acc[i][j][1] = 0.f;
        acc[i][j][2] = 0.f; acc[i][j][3] = 0.f;
      }
    __syncthreads();  // wait for prologue chunk 0
    for (int c = 0; c < NCH; ++c) {
      const __bf16* Pbuf = Plds[c & 1];
      const int k0 = c * 128;
#pragma unroll
      for (int ks = 0; ks < 4; ++ks) {
        bf16x8 ap[4], bv[4];
#pragma unroll
        for (int j = 0; j < 4; ++j)
          bv[j] = *(const bf16x8*)&vtb[(long)(wc * 64 + j * 16 + l15) * SEQ + k0 +
                                       ks * 32 + quad * 8];
#pragma unroll
        for (int i = 0; i < 4; ++i)
          ap[i] = *(const bf16x8*)&Pbuf[(i * 16 + l15) * PSTR + ks * 32 + quad * 8];
#pragma unroll
        for (int i = 0; i < 4; ++i)
#pragma unroll
          for (int j = 0; j < 4; ++j)
            acc[i][j] = __builtin_amdgcn_mfma_f32_16x16x32_bf16(ap[i], bv[j],
                                                                acc[i][j], 0, 0, 0);
      }
      __syncthreads();
    }
    __syncthreads();  // rowsum published

    float rinv[4][4];
#pragma unroll
    for (int i = 0; i < 4; ++i)
#pragma unroll
      for (int r = 0; r < 4; ++r) {
        int row = i * 16 + quad * 4 + r;
        rinv[i][r] = 1.0f / (rsum2[row * 2] + rsum2[row * 2 + 1]);
      }

    __bf16* ob = attn + ((long)b * SEQ + qbase) * H + hbase;
#pragma unroll
    for (int i = 0; i < 4; ++i)
#pragma unroll
      for (int j = 0; j < 4; ++j) {
        const int colL = wc * 64 + j * 16 + l15;
#pragma unroll
        for (int r = 0; r < 4; ++r) {
          const int rowL = i * 16 + quad * 4 + r;
          ob[(long)rowL * H + colL] = (__bf16)(acc[i][j][r] * rinv[i][r]);
        }
      }
  }
}

// ---------------- m97-style GEMM + XOR-swizzled LDS: C = A @ Bt^T (+bias) ----
// OUTMODE: 0 = fp32 row-major, 1 = bf16 row-major, 2 = bf16 transposed batched
//          (Cout layout [BATCH][N][SEQ], rows are per-batch: row = b*SEQ + rb)
template <int OUTMODE, int HASBIAS>
__global__ __launch_bounds__(256) void gemm_bt(
    const __bf16* __restrict__ A, const __bf16* __restrict__ Bt,
    void* __restrict__ Cout, const float* __restrict__ bias, int M, int N, int K) {
  __shared__ __bf16 Alds[128 * 64];
  __shared__ __bf16 Blds[128 * 64];
  const int tid = threadIdx.x;
  const int lane = tid & 63;
  const int w = tid >> 6;
  const int wm = w >> 1, wn = w & 1;
  const int l15 = lane & 15, quad = lane >> 4;
  const long rowBase = (long)blockIdx.y * 128;
  const long colBase = (long)blockIdx.x * 128;

  const int srow = lane >> 3;                 // 0..7
  const int segsw = ((lane & 7) ^ srow) * 8;  // swizzled global k-seg

  const __bf16* ag[4];
  const __bf16* bg[4];
  __bf16* as_[4];
  __bf16* bs_[4];
#pragma unroll
  for (int j = 0; j < 4; ++j) {
    int r = j * 32 + w * 8;
    ag[j] = A + (rowBase + r + srow) * (long)K + segsw;
    bg[j] = Bt + (colBase + r + srow) * (long)K + segsw;
    as_[j] = &Alds[r * 64 + (lane & 7) * 8];
    bs_[j] = &Blds[r * 64 + (lane & 7) * 8];
  }

  f32x4 acc[4][4];
#pragma unroll
  for (int i = 0; i < 4; ++i)
#pragma unroll
    for (int j = 0; j < 4; ++j) {
      acc[i][j][0] = 0.f; acc[i][j][1] = 0.f; acc[i][j][2] = 0.f; acc[i][j][3] = 0.f;
    }

  const int h7 = l15 & 7;

  for (int k0 = 0; k0 < K; k0 += 64) {
#pragma unroll
    for (int j = 0; j < 4; ++j) {
      async_g2l_16(ag[j], as_[j]);
      async_g2l_16(bg[j], bs_[j]);
      ag[j] += 64;
      bg[j] += 64;
    }
    __syncthreads();
#pragma unroll
    for (int s = 0; s < 2; ++s) {
      const int slot = ((s * 4 + quad) ^ h7) * 8;
      bf16x8 af[4], bfv[4];
#pragma unroll
      for (int i = 0; i < 4; ++i) {
        af[i] = *(const bf16x8*)&Alds[(wm * 64 + i * 16 + l15) * 64 + slot];
        bfv[i] = *(const bf16x8*)&Blds[(wn * 64 + i * 16 + l15) * 64 + slot];
      }
#pragma unroll
      for (int i = 0; i < 4; ++i)
#pragma unroll
        for (int j = 0; j < 4; ++j)
          acc[i][j] =
              __builtin_amdgcn_mfma_f32_16x16x32_bf16(af[i], bfv[j], acc[i][j], 0, 0, 0);
    }
    __syncthreads();
  }

  const long crow0 = rowBase + wm * 64 + quad * 4;
  const long ccol0 = colBase + wn * 64 + l15;
#pragma unroll
  for (int i = 0; i < 4; ++i) {
#pragma unroll
    for (int j = 0; j < 4; ++j) {
      long col = ccol0 + j * 16;
      float bb = HASBIAS ? bias[col] : 0.f;
      if (OUTMODE == 2) {
        long row0 = crow0 + i * 16;          // 4 consecutive rows, same batch
        int bz = (int)(row0 >> 11);          // row / SEQ
        long rb = row0 & (SEQ - 1);
        bf16x4 pv;
#pragma unroll
        for (int r = 0; r < 4; ++r) pv[r] = (__bf16)(acc[i][j][r] + bb);
        *(bf16x4*)&((__bf16*)Cout)[((long)bz * N + col) * SEQ + rb] = pv;
      } else {
#pragma unroll
        for (int r = 0; r < 4; ++r) {
          long row = crow0 + i * 16 + r;
          float val = acc[i][j][r] + bb;
          if (OUTMODE == 0)
            ((float*)Cout)[row * N + col] = val;
          else
            ((__bf16*)Cout)[row * N + col] = (__bf16)val;
        }
      }
    }
  }
}

extern "C" void kernel_launch(void* const* d_in, const int* in_sizes, int n_in,
                              void* d_out, int out_size, void* d_ws, size_t ws_size,
                              hipStream_t stream) {
  const float* x = (const float*)d_in[0];
  const float* Wq = (const float*)d_in[1];
  const float* bq = (const float*)d_in[2];
  const float* Wk = (const float*)d_in[3];
  const float* bk = (const float*)d_in[4];
  const float* Wv = (const float*)d_in[5];
  const float* bv = (const float*)d_in[6];
  const float* We = (const float*)d_in[7];
  const float* be = (const float*)d_in[8];
  const float* Wo = (const float*)d_in[9];
  const float* bo = (const float*)d_in[10];
  float* out = (float*)d_out;

  char* ws = (char*)d_ws;
  size_t o = 0;
  auto alloc = [&](size_t n) {
    size_t r = o;
    o += (n + 255) & ~(size_t)255;
    return r;
  };
  __bf16* xbf = (__bf16*)(ws + alloc((size_t)MROWS * H * 2));  // x hi
  __bf16* v_t = (__bf16*)(ws + alloc((size_t)MROWS * H * 2));  // v^T [B][H][S]
  __bf16* attn = (__bf16*)(ws + alloc((size_t)MROWS * H * 2));
  __bf16* Wvt = (__bf16*)(ws + alloc((size_t)H * H * 2));
  __bf16* Wot = (__bf16*)(ws + alloc((size_t)H * H * 2));
  __bf16* Cth = (__bf16*)(ws + alloc((size_t)32 * H * 2));
  __bf16* Ctl = (__bf16*)(ws + alloc((size_t)32 * H * 2));
  float* dvec = (float*)(ws + alloc(32 * 4));
  __bf16* qq32 = (__bf16*)(ws + alloc((size_t)MROWS * 32 * 2));
  __bf16* kk32 = (__bf16*)(ws + alloc((size_t)MROWS * 32 * 2));
  // Alias (stream-ordered lifetime separation):
  __bf16* xlo = attn;  // x lo part: dead before attn is written (fused_attn)
  if (ws_size < o) return;

  // 1) x -> bf16 hi/lo split
  cvt_split<<<MROWS * H / 1024, 256, 0, stream>>>(x, xbf, xlo, MROWS * H);
  // 2) Wv^T, Wo^T as bf16
  transpose_cvt_f32_bf16<<<dim3(32, 32), 256, 0, stream>>>(Wv, Wvt, H, H);
  transpose_cvt_f32_bf16<<<dim3(32, 32), 256, 0, stream>>>(Wo, Wot, H, H);
  // 3) collapsed embed matrices (bf16 hi/lo, Bt layout) + bias fold
  k2_cqk<<<512, 256, 0, stream>>>(Wq, Wk, We, Cth, Ctl);
  k2b_dvec<<<1, 64, 0, stream>>>(bq, bk, We, be, dvec);
  // 4) unit-norm quantum embeds via MFMA -> bf16 [S][32] zero-padded
  k3_embed_mfma<<<MROWS / 32, 256, 0, stream>>>(xbf, xlo, Cth, Ctl, dvec, qq32, kk32);
  // 5) v = x@Wv + bv, written TRANSPOSED per batch -> v_t[b][h][s]
  gemm_bt<2, 1><<<dim3(8, 64), 256, 0, stream>>>(xbf, Wvt, v_t, bv, MROWS, H, H);
  // 6) fused attention: producer/consumer waves, 64q x 256h tiles
  fused_attn<<<dim3(H / 256, SEQ / 64, BATCH), 512, 0, stream>>>(qq32, kk32, v_t,
                                                                 attn);
  // 7) out = attended @ Wo + bo  (fp32 out)
  gemm_bt<0, 1><<<dim3(8, 64), 256, 0, stream>>>(attn, Wot, out, bo, MROWS, H, H);
}